// Round 1
// baseline (114.277 us; speedup 1.0000x reference)
//
#include <hip/hip_runtime.h>
#include <hip/hip_bf16.h>
#include <cstdint>

typedef __hip_bfloat16 bf16;
using bf16x8 = __attribute__((ext_vector_type(8))) short;  // 8 bf16 (4 VGPRs)
using f32x4  = __attribute__((ext_vector_type(4))) float;

#define HW_T 4096   // H*W = 64*64
#define B_T  4

__device__ __forceinline__ short f2bs(float f) {
    bf16 h = __float2bfloat16(f);
    return *reinterpret_cast<short*>(&h);
}
__device__ __forceinline__ float bs2f(unsigned short s) {
    unsigned int u = ((unsigned int)s) << 16;
    float f;
    __builtin_memcpy(&f, &u, 4);
    return f;
}

// ---------------------------------------------------------------------------
// Prep (448 blocks):
//  blocks 0..319: fused weight row, emitted in fragment layout Wf[kb][row][8].
//   HV rows are stored INTERLEAVED: row 64 + dh*4 + n  (so attn_qy reads
//   HV[n=0..3] for fixed (l, dh) as one contiguous b64).
//    logits: row n*16+q      = sum_d dot_w[n,q,d] * kv_w[n*64+d, c]
//    hv:     row 64+dh*4+n   = sum_dd head_w[dh, n*64+dd] * kv_w[256+n*64+dd, c]
//  blocks 320..447: qwF fragment-layout convert:
//    qwF[(kb*256 + ch)*8 + j] = q_w[ch*1024 + kb*8 + j]
// ---------------------------------------------------------------------------
__global__ __launch_bounds__(256) void fuse_all(
    const float* __restrict__ kv_w, const float* __restrict__ dot_w,
    const float* __restrict__ head_w, const float* __restrict__ q_w,
    bf16* __restrict__ Wf, bf16* __restrict__ qwF)
{
    const int rb = blockIdx.x;
    if (rb < 320) {
        const int r = rb, c = threadIdx.x;
        float acc = 0.f;
        int rowIdx;
        if (r < 64) {
            const int n = r >> 4, q = r & 15;
            #pragma unroll 8
            for (int d = 0; d < 64; ++d)
                acc += dot_w[(n * 16 + q) * 64 + d] * kv_w[(size_t)(n * 64 + d) * 256 + c];
            rowIdx = r;
        } else {
            const int rr = r - 64, n = rr >> 6, dh = rr & 63;
            #pragma unroll 8
            for (int dd = 0; dd < 64; ++dd)
                acc += head_w[dh * 256 + n * 64 + dd] * kv_w[(size_t)(256 + n * 64 + dd) * 256 + c];
            rowIdx = 64 + dh * 4 + n;   // interleaved HV layout
        }
        Wf[((size_t)(c >> 3) * 320 + rowIdx) * 8 + (c & 7)] = __float2bfloat16(acc);
    } else {
        const int t  = (rb - 320) * 256 + threadIdx.x;  // 0..32767 = kb*256 + ch
        const int ch = t & 255, kb = t >> 8;
        const float* src = q_w + (size_t)ch * 1024 + kb * 8;
        bf16x8 pk;
        #pragma unroll
        for (int j = 0; j < 8; ++j) pk[j] = f2bs(src[j]);
        *(bf16x8*)&qwF[(size_t)t * 8] = pk;
    }
}

// ---------------------------------------------------------------------------
// K1: AH (b, p, 320) bf16 = x^T (on-the-fly transpose of fp32 x) * W^T.
// Tile 32 px x 320 ch (full N), BK=64, 256 threads (4 waves x 80 ch), fully
// unrolled 4-iter K-loop, double-buffered 4KB A tile (one ds_write_b128 per
// thread per iter), B-fragments streamed from Wf in L2 with register
// prefetch. 2 KB/wave of x-loads in flight per iter. Grid 128 x 4 (2/CU).
// ---------------------------------------------------------------------------
__global__ __launch_bounds__(256) void gemm_xw(
    const float* __restrict__ x, const bf16* __restrict__ Wf,
    bf16* __restrict__ AH)
{
    __shared__ __align__(16) bf16 As[2][8][32][8];   // [buf][ch8][px][ch&7] 2x4KB
    const int tid  = threadIdx.x;
    const int lane = tid & 63;
    const int wave = tid >> 6;
    const int p0 = blockIdx.x * 32;
    const int b  = blockIdx.y;
    const float* xb = x + (size_t)b * 256 * HW_T;
    const int fi = lane & 15, quad = lane >> 4;
    const int wn0 = wave * 80;

    const int spx = tid & 31, sc8 = tid >> 5;   // staging: pixel, ch-octet 0..7

    f32x4 acc[2][5] = {};
    float xr[8];
    bf16x8 bcur[2][5], bnxt[2][5];

    {   // prologue: stage iter 0 (A -> LDS buf0, B -> regs)
        const float* xp = xb + (size_t)(sc8 * 8) * HW_T + p0 + spx;
        #pragma unroll
        for (int j = 0; j < 8; ++j) xr[j] = xp[(size_t)j * HW_T];
        #pragma unroll
        for (int c = 0; c < 2; ++c)
            #pragma unroll
            for (int j = 0; j < 5; ++j)
                bcur[c][j] = *(const bf16x8*)
                    &Wf[((size_t)(c * 4 + quad) * 320 + wn0 + j * 16 + fi) * 8];
        bf16x8 pk;
        #pragma unroll
        for (int j = 0; j < 8; ++j) pk[j] = f2bs(xr[j]);
        *(bf16x8*)&As[0][sc8][spx][0] = pk;
    }

    #pragma unroll
    for (int it = 0; it < 4; ++it) {
        const int cur = it & 1;
        __syncthreads();                       // As[cur] ready
        if (it < 3) {
            const int k1 = (it + 1) * 64;
            const float* xp = xb + (size_t)(k1 + sc8 * 8) * HW_T + p0 + spx;
            #pragma unroll
            for (int j = 0; j < 8; ++j) xr[j] = xp[(size_t)j * HW_T];
            #pragma unroll
            for (int c = 0; c < 2; ++c)
                #pragma unroll
                for (int j = 0; j < 5; ++j)
                    bnxt[c][j] = *(const bf16x8*)
                        &Wf[((size_t)((k1 >> 3) + c * 4 + quad) * 320 + wn0 + j * 16 + fi) * 8];
        }
        #pragma unroll
        for (int c = 0; c < 2; ++c) {
            bf16x8 af[2];
            #pragma unroll
            for (int i = 0; i < 2; ++i)
                af[i] = *(const bf16x8*)&As[cur][c * 4 + quad][i * 16 + fi][0];
            #pragma unroll
            for (int i = 0; i < 2; ++i)
                #pragma unroll
                for (int j = 0; j < 5; ++j)
                    acc[i][j] = __builtin_amdgcn_mfma_f32_16x16x32_bf16(
                        af[i], bcur[c][j], acc[i][j], 0, 0, 0);
        }
        if (it < 3) {
            bf16x8 pk;
            #pragma unroll
            for (int j = 0; j < 8; ++j) pk[j] = f2bs(xr[j]);
            *(bf16x8*)&As[cur ^ 1][sc8][spx][0] = pk;
            #pragma unroll
            for (int c = 0; c < 2; ++c)
                #pragma unroll
                for (int j = 0; j < 5; ++j) bcur[c][j] = bnxt[c][j];
        }
    }

    bf16* Cp = AH + ((size_t)b * HW_T + p0) * 320;
    #pragma unroll
    for (int i = 0; i < 2; ++i) {
        const int pl = i * 16 + quad * 4;      // local pixel row
        #pragma unroll
        for (int r = 0; r < 4; ++r)
            #pragma unroll
            for (int j = 0; j < 5; ++j)
                Cp[(size_t)(pl + r) * 320 + wn0 + j * 16 + fi] =
                    __float2bfloat16(acc[i][j][r]);
    }
}

// ---------------------------------------------------------------------------
// Fused K4+K5: block = one full 64-px row, 512 threads (8 waves, 8 px/wave).
// Grid 256 (1 block/CU, 8 waves/CU = same occupancy as previous 2x(4-wave)).
// AH (b,p,320) bf16: ch 0..63 = logits (n*16+q), ch 64..319 = hv INTERLEAVED
// (64 + d*4 + n).
// Phase 1 (barrier-free; per-wave bf16 P scratch, same-wave DS in-order):
//   softmax over 9 zero-padded window logits; y(16q x 64d) = P(16x36) @
//   HV(36x64) as 4 MFMAs (l=0..7) + one zero-padded MFMA for the l=8 tail
//   (replaces the old fp32 tail: -64 fmaf -16 LDS reads per px per lane);
//   y -> LDS [64][YPAD] bf16 with XOR-swizzled ch (conflict-free stores).
// Phase 2: z tile (256 ch x 64 px, K=1024): wave owns 32 ch x 64 px; A from
//   qwF (fragment layout, register prefetch; 2x reuse vs 32-px blocks halves
//   qwF L2 stream 268MB->134MB), B via ds_read_b128 from yL (same swizzle).
//   Single barrier between phases.
// ---------------------------------------------------------------------------
#define YPAD 1032
#define PSTR 72     // Pm stride in bf16: l*PSTR/2 dwords == 4*l mod 32 -> quads
                    // land 8 banks apart on the A-fragment gather (2-way, free)
#define ATTN_LDS (64 * YPAD * 2 + 8 * 9 * PSTR * 2)   // 132096 + 10368 = 142464

// yL channel swizzle: toggle bf16 bits 4-5 by (ch>>8)&3.  Stores (ch =
// quad*256 + r*64 + dt*16 + fi) land on banks 8*(dt^quad) + fi>>1 -> all 32
// banks, 2-way.  Involution; 8-aligned runs of 8 bf16 stay contiguous, so
// phase-2 ds_read_b128 at (k0 + quad*8) just applies the same XOR.
__device__ __forceinline__ int ysw(int ch) {
    return ch ^ (((ch >> 8) & 3) << 4);
}

__global__ __launch_bounds__(512) void attn_qy(
    const bf16* __restrict__ AH, const float* __restrict__ head_b,
    const bf16* __restrict__ qwF, const float* __restrict__ q_b,
    float* __restrict__ z)
{
    extern __shared__ __align__(16) char smem[];
    bf16*  yL  = (bf16*)smem;                            // [64][YPAD], swizzled ch
    short* Pmb = (short*)(smem + 64 * YPAD * 2) + (threadIdx.x >> 6) * 9 * PSTR;

    const int tid  = threadIdx.x;
    const int wave = tid >> 6, lane = tid & 63;
    const int h    = blockIdx.x & 63;
    const int b    = blockIdx.x >> 6;
    const int fi = lane & 15, quad = lane >> 4;
    const ushort* AHu = (const ushort*)AH;

    float hb[4];
    #pragma unroll
    for (int dt = 0; dt < 4; ++dt) hb[dt] = head_b[dt * 16 + fi];

    // ---------------- phase 1 (barrier-free) ----------------
    for (int pi = 0; pi < 8; ++pi) {
        const int lp = wave * 8 + pi;      // local pixel 0..63 == w
        const int w  = lp;
        int off[9]; float okf[9];
        #pragma unroll
        for (int l = 0; l < 9; ++l) {
            const int i = l / 3, j = l % 3;
            const int hh = h + i - 1, ww = w + j - 1;
            const bool ok = ((unsigned)hh < 64u) && ((unsigned)ww < 64u);
            off[l] = ((b << 12) + (ok ? hh : h) * 64 + (ok ? ww : w)) * 320;
            okf[l] = ok ? 1.0f : 0.0f;
        }
        {   // softmax over zero-padded logits (lane = n*16+q), P stored bf16
            float lg[9];
            #pragma unroll
            for (int l = 0; l < 9; ++l)
                lg[l] = bs2f(AHu[(size_t)off[l] + lane]) * okf[l];
            float m = lg[0];
            #pragma unroll
            for (int l = 1; l < 9; ++l) m = fmaxf(m, lg[l]);
            float e[9], s = 0.f;
            #pragma unroll
            for (int l = 0; l < 9; ++l) { e[l] = __expf(lg[l] - m); s += e[l]; }
            const float inv = 1.0f / s;
            #pragma unroll
            for (int l = 0; l < 9; ++l)
                Pmb[l * PSTR + lane] = f2bs(e[l] * inv * okf[l]);
        }
        // same-wave DS write->read is in-order; no barrier needed

        // A-fragment: P[q=fi][k=quad*8+j], k=(l,n): l=k>>2, n=k&3 (l<8)
        bf16x8 afr;
        #pragma unroll
        for (int j = 0; j < 8; ++j) {
            const int k = quad * 8 + j;
            afr[j] = Pmb[(k >> 2) * PSTR + (k & 3) * 16 + fi];
        }
        // zero-padded tail fragment: k2=32+quad*8+j -> only quad0, j<4 (l=8)
        bf16x8 afr2;
        #pragma unroll
        for (int j = 0; j < 8; ++j) afr2[j] = 0;
        #pragma unroll
        for (int j = 0; j < 4; ++j)
            afr2[j] = (quad == 0) ? Pmb[8 * PSTR + j * 16 + fi] : (short)0;

        f32x4 acc[4];
        #pragma unroll
        for (int dt = 0; dt < 4; ++dt) {
            acc[dt][0] = hb[dt]; acc[dt][1] = hb[dt];
            acc[dt][2] = hb[dt]; acc[dt][3] = hb[dt];
        }
        #pragma unroll
        for (int dt = 0; dt < 4; ++dt) {
            const int d = dt * 16 + fi;
            // HV interleaved: rows 64 + d*4 + n -> n=0..3 contiguous (b64)
            const ushort4 u0 = *(const ushort4*)&AHu[(size_t)off[quad * 2]     + 64 + d * 4];
            const ushort4 u1 = *(const ushort4*)&AHu[(size_t)off[quad * 2 + 1] + 64 + d * 4];
            bf16x8 bfr;
            bfr[0] = (short)u0.x; bfr[1] = (short)u0.y;
            bfr[2] = (short)u0.z; bfr[3] = (short)u0.w;
            bfr[4] = (short)u1.x; bfr[5] = (short)u1.y;
            bfr[6] = (short)u1.z; bfr[7] = (short)u1.w;
            acc[dt] = __builtin_amdgcn_mfma_f32_16x16x32_bf16(afr, bfr, acc[dt], 0, 0, 0);
            // l=8 tail as zero-padded MFMA (rows k2=32..35 live in quad0 only)
            const ushort4 u8v = *(const ushort4*)&AHu[(size_t)off[8] + 64 + d * 4];
            bf16x8 bfr2;
            #pragma unroll
            for (int j = 0; j < 8; ++j) bfr2[j] = 0;
            if (quad == 0) {
                bfr2[0] = (short)u8v.x; bfr2[1] = (short)u8v.y;
                bfr2[2] = (short)u8v.z; bfr2[3] = (short)u8v.w;
            }
            acc[dt] = __builtin_amdgcn_mfma_f32_16x16x32_bf16(afr2, bfr2, acc[dt], 0, 0, 0);
        }
        // y -> LDS, swizzled: ch = q*64 + d = quad*256 + r*64 + dt*16 + fi
        #pragma unroll
        for (int dt = 0; dt < 4; ++dt)
            #pragma unroll
            for (int r = 0; r < 4; ++r) {
                const int ch = quad * 256 + r * 64 + dt * 16 + fi;
                yL[(size_t)lp * YPAD + ysw(ch)] = __float2bfloat16(acc[dt][r]);
            }
    }
    __syncthreads();   // y tile complete (cross-wave)

    // ---------------- phase 2: z = qw @ y^T + q_b ----------------
    f32x4 zacc[2][4] = {};
    bf16x8 af[2], afn[2];
    #pragma unroll
    for (int i = 0; i < 2; ++i)
        af[i] = *(const bf16x8*)&qwF[((size_t)quad * 256 + wave * 32 + i * 16 + fi) * 8];

    #pragma unroll 2
    for (int k0 = 0; k0 < 1024; k0 += 32) {
        if (k0 < 992) {
            const size_t kb = (size_t)((k0 + 32) >> 3) + quad;
            #pragma unroll
            for (int i = 0; i < 2; ++i)
                afn[i] = *(const bf16x8*)&qwF[(kb * 256 + wave * 32 + i * 16 + fi) * 8];
        }
        const int chs = ysw(k0 + quad * 8);
        bf16x8 bfr[4];
        #pragma unroll
        for (int j = 0; j < 4; ++j)
            bfr[j] = *(const bf16x8*)&yL[(size_t)(j * 16 + fi) * YPAD + chs];
        #pragma unroll
        for (int i = 0; i < 2; ++i)
            #pragma unroll
            for (int j = 0; j < 4; ++j)
                zacc[i][j] = __builtin_amdgcn_mfma_f32_16x16x32_bf16(
                    af[i], bfr[j], zacc[i][j], 0, 0, 0);
        if (k0 < 992) {
            #pragma unroll
            for (int i = 0; i < 2; ++i) af[i] = afn[i];
        }
    }

    const int hw0 = h * 64;
    #pragma unroll
    for (int i = 0; i < 2; ++i) {
        const int row0 = wave * 32 + i * 16 + quad * 4;
        #pragma unroll
        for (int r = 0; r < 4; ++r) {
            const float bv = q_b[row0 + r];
            #pragma unroll
            for (int j = 0; j < 4; ++j)
                z[((size_t)(b * 256 + row0 + r)) * HW_T + hw0 + j * 16 + fi] =
                    zacc[i][j][r] + bv;
        }
    }
}

// ---------------------------------------------------------------------------
extern "C" void kernel_launch(void* const* d_in, const int* in_sizes, int n_in,
                              void* d_out, int out_size, void* d_ws, size_t ws_size,
                              hipStream_t stream) {
    (void)in_sizes; (void)n_in; (void)out_size; (void)ws_size;
    const float* x      = (const float*)d_in[0];   // (4,256,64,64)
    const float* kv_w   = (const float*)d_in[1];   // (512,256)
    const float* dot_w  = (const float*)d_in[2];   // (4,16,64)
    const float* head_w = (const float*)d_in[3];   // (64,256)
    const float* head_b = (const float*)d_in[4];   // (64,)
    const float* q_w    = (const float*)d_in[5];   // (256,1024)
    const float* q_b    = (const float*)d_in[6];   // (256,)
    float* z = (float*)d_out;                      // (4,256,64,64)

    // workspace (11.2 MB):
    //   AH   bf16 (B,4096,320) 10485760 B @ 0
    //   qwF  bf16 (128,256,8)    524288 B @ 10485760
    //   Wf   bf16 (32,320,8)     163840 B @ 11010048
    char* ws   = (char*)d_ws;
    bf16*  AH  = (bf16*)ws;
    bf16*  qwF = (bf16*)(ws + 10485760);
    bf16*  Wf  = (bf16*)(ws + 11010048);

    // opt-in to >64KB dynamic LDS for the fused kernel (idempotent, host-side)
    static bool attr_done = []() {
        hipFuncSetAttribute((const void*)attn_qy,
                            hipFuncAttributeMaxDynamicSharedMemorySize, ATTN_LDS);
        return true;
    }();
    (void)attr_done;

    fuse_all<<<dim3(448), 256, 0, stream>>>(kv_w, dot_w, head_w, q_w, Wf, qwF);

    // K1: AH = x^T @ W^T  (M=4096/batch, N=320, K=256), transpose fused, bf16 out
    gemm_xw<<<dim3(128, B_T), 256, 0, stream>>>(x, Wf, AH);

    // K4+K5 fused: softmax/apply + z = qw @ y^T + q_b (y never leaves LDS)
    attn_qy<<<dim3(256), 512, ATTN_LDS, stream>>>(AH, head_b, qwF, q_b, z);
}